// Round 15
// baseline (114.386 us; speedup 1.0000x reference)
//
#include <hip/hip_runtime.h>
#include <math.h>

#define NPOS  16384
#define LBAG  30
#define NFEAT 40960
#define HDIM  512          // per side
#define MT    16           // positions per block (mlp2)
#define THR   20480        // id-range phase split (half the table)

typedef short bf16x8 __attribute__((ext_vector_type(8)));
typedef float f32x4  __attribute__((ext_vector_type(4)));
typedef float f32x2  __attribute__((ext_vector_type(2)));

__device__ __forceinline__ unsigned int f2bf(float f) {
    unsigned int u = __float_as_uint(f);
    return (u + 0x7fffu + ((u >> 16) & 1u)) >> 16;
}
__device__ __forceinline__ float clip01(float v) { return fminf(fmaxf(v, 0.f), 1.f); }

// one VOP3P instr = two independent fp32 adds (CDNA4)
__device__ __forceinline__ f32x2 pk_add(f32x2 a, f32x2 b) {
    f32x2 d;
    asm("v_pk_add_f32 %0, %1, %2" : "=v"(d) : "v"(a), "v"(b));
    return d;
}
// unpack one uint holding 2 bf16 -> {lo,hi} fp32 pair
__device__ __forceinline__ f32x2 bf2f2(unsigned int u) {
    f32x2 r;
    r.x = __uint_as_float(u << 16);
    r.y = __uint_as_float(u & 0xffff0000u);
    return r;
}

// ---------------------------------------------------------------------------
// Prep 1: emb fp32 -> bf16 single table [NFEAT][512] (uint pairs). ~20us
// (126 MB moved, at the HBM floor).
// ---------------------------------------------------------------------------
__global__ __launch_bounds__(256) void cvt_emb(const float* __restrict__ src,
                                               unsigned int* __restrict__ dst) {
    const int nchunk = NFEAT * HDIM / 8;
    int c = blockIdx.x * 256 + threadIdx.x;
    const int stride = gridDim.x * 256;
    for (; c < nchunk; c += stride) {
        float4 f0 = ((const float4*)src)[(size_t)c * 2];
        float4 f1 = ((const float4*)src)[(size_t)c * 2 + 1];
        uint4 o;
        o.x = f2bf(f0.x) | (f2bf(f0.y) << 16);
        o.y = f2bf(f0.z) | (f2bf(f0.w) << 16);
        o.z = f2bf(f1.x) | (f2bf(f1.y) << 16);
        o.w = f2bf(f1.z) | (f2bf(f1.w) << 16);
        ((uint4*)dst)[c] = o;
    }
}

// ---------------------------------------------------------------------------
// Prep 2: W1 [128][1024] fp32 -> bf16 in MFMA B-fragment order.
//   B[k][j] = W1[j][k], j = nf*16 + (lane&15), k = ks*32 + (lane>>4)*8 + b
// ---------------------------------------------------------------------------
__global__ __launch_bounds__(256) void prep_w1(const float* __restrict__ W1,
                                               unsigned int* __restrict__ dst) {
    int c = blockIdx.x * 256 + threadIdx.x;
    if (c >= 8 * 32 * 64) return;
    int l  = c & 63;
    int ks = (c >> 6) & 31;
    int nf = c >> 11;
    int o  = nf * 16 + (l & 15);
    int kb = ks * 32 + (l >> 4) * 8;
    float4 f0 = *(const float4*)(W1 + (size_t)o * 1024 + kb);
    float4 f1 = *(const float4*)(W1 + (size_t)o * 1024 + kb + 4);
    uint4 v;
    v.x = f2bf(f0.x) | (f2bf(f0.y) << 16);
    v.y = f2bf(f0.z) | (f2bf(f0.w) << 16);
    v.z = f2bf(f1.x) | (f2bf(f1.y) << 16);
    v.w = f2bf(f1.z) | (f2bf(f1.w) << 16);
    ((uint4*)dst)[c] = v;
}

// ---------------------------------------------------------------------------
// Kernel 1, round 15: r14's XCD-sliced + 2-phase gather, polished:
//  (1) v_pk_add_f32 accumulate (f32x2 pairs): 12 instead of 16 VALU per 16B
//      (r14: VALUBusy 52% -> VALU-issue is now a major term). Same adds,
//      same order -> bit-identical output (validity check: absmax must stay
//      exactly 1.953e-3).
//  (2) sidx16 layout [r][128] instead of [bag][32]: r14's id reads had ALL
//      8 lane-groups on one bank (bag stride 64B -> 8-way conflict, 1.7M
//      SQ_LDS_BANK_CONFLICT); [r][bag] makes groups read adjacent dwords /
//      broadcast -> conflict-free.
// Structure, occupancy, traffic identical to r14 (FETCH ~50MB compulsory).
// ---------------------------------------------------------------------------
__global__ __launch_bounds__(256) void gather_slices(
    const int* __restrict__ stm_idx, const int* __restrict__ nstm_idx,
    const unsigned int* __restrict__ embbf,     // [NFEAT][256] uints (512 bf16)
    unsigned int* __restrict__ xg)              // [NPOS][512] uints, swizzled
{
    __shared__ unsigned short sidx16[32 * 128]; // [r][bag]
    __shared__ int nlo[128];

    const int t     = threadIdx.x;
    const int slice = blockIdx.x & 7;
    const int pblk  = (blockIdx.x >> 3) * 64;

    // ---- stage + partition indices (thread b -> bag b); lo ids at r=0..,
    //      hi ids at r=29.. (descending) ----
    if (t < 128) {
        const int p    = t >> 1;
        const int side = t & 1;
        const int* src = (side ? nstm_idx : stm_idx) + (size_t)(pblk + p) * 30;
        int lo = 0, hi = 29;
#pragma unroll
        for (int r = 0; r < 30; ++r) {
            const int id = src[r];
            if (id < THR) sidx16[(lo++) * 128 + t] = (unsigned short)id;
            else          sidx16[(hi--) * 128 + t] = (unsigned short)id;
        }
        nlo[t] = lo;
    }
    __syncthreads();

    const int lane = t & 63, w = t >> 6;
    const int g  = lane >> 3;                   // lane-group 0..7 (one bag)
    const int li = lane & 7;                    // 16B chunk within 128B line
    const unsigned int tabofs = slice * 32 + li * 4;

    f32x2 ac[4][4];
#pragma unroll
    for (int it = 0; it < 4; ++it)
#pragma unroll
        for (int j = 0; j < 4; ++j) ac[it][j] = (f32x2){0.f, 0.f};

#define ACCUM(it, bag)                                                        \
    do {                                                                      \
        const unsigned int id = sidx16[r * 128 + (bag)];                      \
        const uint4 v = *(const uint4*)(embbf + (size_t)id * 256 + tabofs);   \
        ac[it][0] = pk_add(ac[it][0], bf2f2(v.x));                            \
        ac[it][1] = pk_add(ac[it][1], bf2f2(v.y));                            \
        ac[it][2] = pk_add(ac[it][2], bf2f2(v.z));                            \
        ac[it][3] = pk_add(ac[it][3], bf2f2(v.w));                            \
    } while (0)

    // ---- PHASE A: low-id rows (table rows [0,THR) = 2.56MB/XCD slice) ----
#pragma unroll
    for (int it = 0; it < 4; ++it) {
        const int bag = it * 32 + w * 8 + g;
        const int n = nlo[bag];
        for (int r = 0; r < n; ++r) ACCUM(it, bag);
    }
    __syncthreads();    // align phases within block (chip-wide: co-residency)

    // ---- PHASE B: high-id rows + writeout ----
#pragma unroll
    for (int it = 0; it < 4; ++it) {
        const int bag = it * 32 + w * 8 + g;
        const int n = nlo[bag];
        for (int r = n; r < 30; ++r) ACCUM(it, bag);

        const int p    = bag >> 1;
        const int side = bag & 1;
        uint4 pk;
        pk.x = f2bf(clip01(ac[it][0].x)) | (f2bf(clip01(ac[it][0].y)) << 16);
        pk.y = f2bf(clip01(ac[it][1].x)) | (f2bf(clip01(ac[it][1].y)) << 16);
        pk.z = f2bf(clip01(ac[it][2].x)) | (f2bf(clip01(ac[it][2].y)) << 16);
        pk.w = f2bf(clip01(ac[it][3].x)) | (f2bf(clip01(ac[it][3].y)) << 16);
        const int colb = (side * 1024 + slice * 128 + li * 16) ^ ((p & 7) << 4);
        *(uint4*)((char*)xg + (size_t)(pblk + p) * 2048 + colb) = pk;
    }
#undef ACCUM
}

// ---------------------------------------------------------------------------
// Kernel 2: MLP. x arrives already in the swizzled LDS layout -> linear 32KB
// stage. MFMA layer1 + layers 2/3 identical to r9-r14 (verified).
// ---------------------------------------------------------------------------
__global__ __launch_bounds__(256, 4) void mlp2(
    const unsigned int* __restrict__ xg,        // [NPOS][512] uints, swizzled
    const unsigned int* __restrict__ w1f,       // frag-ordered bf16
    const float* __restrict__ b1,
    const float* __restrict__ W2, const float* __restrict__ b2,
    const float* __restrict__ W3, const float* __restrict__ b3,
    float* __restrict__ out)
{
    __shared__ __align__(16) char smem[32768];
    char* xb   = smem;
    float* h1  = (float*)smem;                  // [16][132]
    float* w2  = (float*)smem + 16 * 132;       // [32][132]
    float* h2  = (float*)smem + 48 * 132;       // [16][33]

    const int t    = threadIdx.x;               // 0..255
    const int pblk = blockIdx.x * MT;
    const int w    = t >> 6;
    const int lane = t & 63;

    // ---- stage x tile: linear 32KB copy ----
    {
        const uint4* src = (const uint4*)((const char*)xg + (size_t)pblk * 2048);
#pragma unroll
        for (int i = 0; i < 8; ++i) {
            int f = t + i * 256;
            *(uint4*)(xb + f * 16) = src[f];
        }
    }
    __syncthreads();

    // ---- layer1 GEMM via MFMA (M=16, N=128, K=1024) ----
    const int l15 = lane & 15, lg = lane >> 4, lq = lane & 7;
    f32x4 acc0 = {}, acc1 = {};
    const int arow = l15 * 2048;
    const bf16x8* w1v = (const bf16x8*)w1f;
#pragma unroll 4
    for (int ks = 0; ks < 32; ++ks) {
        const int acol = (ks * 64 + lg * 16) ^ (lq << 4);
        bf16x8 a0  = *(const bf16x8*)(xb + arow + acol);
        bf16x8 bf0 = w1v[((2 * w + 0) * 32 + ks) * 64 + lane];
        bf16x8 bf1 = w1v[((2 * w + 1) * 32 + ks) * 64 + lane];
        acc0 = __builtin_amdgcn_mfma_f32_16x16x32_bf16(a0, bf0, acc0, 0, 0, 0);
        acc1 = __builtin_amdgcn_mfma_f32_16x16x32_bf16(a0, bf1, acc1, 0, 0, 0);
    }
    __syncthreads();   // x tile dead; smem becomes h1/w2/h2

    // ---- epilogue: bias + clip -> h1[16][132] ----
    {
        const int o0 = (2 * w + 0) * 16 + l15;
        const int o1 = (2 * w + 1) * 16 + l15;
        const float bb0 = b1[o0], bb1 = b1[o1];
#pragma unroll
        for (int r = 0; r < 4; ++r) {
            int p0 = lg * 4 + r;
            h1[p0 * 132 + o0] = clip01(acc0[r] + bb0);
            h1[p0 * 132 + o1] = clip01(acc1[r] + bb1);
        }
    }
    // stage W2 (32x128)
#pragma unroll
    for (int i = 0; i < 16; ++i) {
        int f = t + i * 256;
        int o = f >> 7, k = f & 127;
        w2[o * 132 + k] = W2[o * 128 + k];
    }
    __syncthreads();

    // ---- layer2: 16 pos x 32 out ----
    {
        const int p2 = t >> 4;
        const int ob = (t & 15) * 2;
        float s0 = b2[ob], s1 = b2[ob + 1];
#pragma unroll
        for (int k4 = 0; k4 < 32; ++k4) {
            float4 h4 = *(const float4*)(h1 + p2 * 132 + k4 * 4);
            float4 wa = *(const float4*)(w2 + ob * 132 + k4 * 4);
            float4 wb = *(const float4*)(w2 + (ob + 1) * 132 + k4 * 4);
            s0 += h4.x * wa.x + h4.y * wa.y + h4.z * wa.z + h4.w * wa.w;
            s1 += h4.x * wb.x + h4.y * wb.y + h4.z * wb.z + h4.w * wb.w;
        }
        h2[p2 * 33 + ob]     = clip01(s0);
        h2[p2 * 33 + ob + 1] = clip01(s1);
    }
    __syncthreads();

    // ---- layer3 + tanh ----
    if (t < MT) {
        float s = b3[0];
#pragma unroll
        for (int k = 0; k < 32; ++k) s += h2[t * 33 + k] * W3[k];
        out[pblk + t] = tanhf(s);
    }
}

// ---------------------------------------------------------------------------
extern "C" void kernel_launch(void* const* d_in, const int* in_sizes, int n_in,
                              void* d_out, int out_size, void* d_ws, size_t ws_size,
                              hipStream_t stream) {
    const int*   stm_idx  = (const int*)  d_in[0];
    const int*   nstm_idx = (const int*)  d_in[2];
    const float* emb      = (const float*)d_in[4];
    const float* W1       = (const float*)d_in[5];
    const float* b1       = (const float*)d_in[6];
    const float* W2       = (const float*)d_in[7];
    const float* b2       = (const float*)d_in[8];
    const float* W3       = (const float*)d_in[9];
    const float* b3       = (const float*)d_in[10];
    float*       out      = (float*)d_out;

    unsigned int* embbf = (unsigned int*)d_ws;                        // 41,943,040 B
    unsigned int* w1f   = (unsigned int*)((char*)d_ws + 41943040);    //    262,144 B
    unsigned int* xg    = (unsigned int*)((char*)d_ws + 42205184);    // 33,554,432 B

    cvt_emb<<<2048, 256, 0, stream>>>(emb, embbf);
    prep_w1<<<64, 256, 0, stream>>>(W1, w1f);
    gather_slices<<<2048, 256, 0, stream>>>(stm_idx, nstm_idx, embbf, xg);
    mlp2<<<NPOS / MT, 256, 0, stream>>>(xg, w1f, b1, W2, b2, W3, b3, out);
}